// Round 10
// baseline (416.234 us; speedup 1.0000x reference)
//
#include <hip/hip_runtime.h>
#include <math.h>

// R9 measured: 412us, conflicts 0, MfmaUtil 33%, ~763 TF eff (85% of the
// m97-structure ceiling). Binder: single-buffer 2-barrier K-loop with
// vmcnt(0) drain + only ~1.85 blocks/CU (Occ 23%) -> no independent wave
// to hide the drain. R10: __launch_bounds__(256,3) -> 3 blocks/CU
// (VGPR cap ~170 >= ~140 used; LDS 33KB allows 4). Single variable.

typedef __bf16 bf16;
typedef bf16 bf16x2 __attribute__((ext_vector_type(2)));
typedef bf16 bf16x4 __attribute__((ext_vector_type(4)));
typedef bf16 bf16x8 __attribute__((ext_vector_type(8)));
typedef float f32x4 __attribute__((ext_vector_type(4)));

#define EPS_Q 1e-8f

constexpr int BM = 128, BN = 128, BK = 32;

__device__ __forceinline__ void gload16(const void* g, void* l) {
    __builtin_amdgcn_global_load_lds(
        (const __attribute__((address_space(1))) unsigned int*)g,
        (__attribute__((address_space(3))) unsigned int*)l, 16, 0, 0);
}

// ---------------------------------------------------------------- prep
// X [MT*128][KT*32] f32 -> tiled hi/lo. grid (KT, MT)
__global__ __launch_bounds__(256)
void split_ew_tiled(const float* __restrict__ in, bf16* __restrict__ h,
                    bf16* __restrict__ l, int K)
{
    const int t = threadIdx.x;
    #pragma unroll
    for (int i = 0; i < 2; ++i) {
        const int s   = t + i * 256;
        const int row = s >> 2;
        const int kc  = s & 3;
        const float* src = in + (size_t)(blockIdx.y * 128 + row) * K
                              + blockIdx.x * 32 + kc * 8;
        const f32x4 v0 = *reinterpret_cast<const f32x4*>(src);
        const f32x4 v1 = *reinterpret_cast<const f32x4*>(src + 4);
        bf16x8 hh, ll;
        #pragma unroll
        for (int e = 0; e < 4; ++e) {
            const bf16 b0 = (bf16)v0[e];
            hh[e] = b0; ll[e] = (bf16)(v0[e] - (float)b0);
            const bf16 b1 = (bf16)v1[e];
            hh[e + 4] = b1; ll[e + 4] = (bf16)(v1[e] - (float)b1);
        }
        const int slot = row * 4 + ((kc + (row >> 1)) & 3);
        const size_t base = ((size_t)blockIdx.y * gridDim.x + blockIdx.x) * 4096
                          + slot * 8;
        *reinterpret_cast<bf16x8*>(h + base) = hh;
        *reinterpret_cast<bf16x8*>(l + base) = ll;
    }
}

// src [K][Ncols] f32 -> tiled hi/lo over [Ncols][K] (transpose). grid (KT, NT)
__global__ __launch_bounds__(256)
void split_tr_tiled(const float* __restrict__ in, bf16* __restrict__ h,
                    bf16* __restrict__ l, int Ncols)
{
    const int t = threadIdx.x;
    #pragma unroll
    for (int i = 0; i < 2; ++i) {
        const int s   = t + i * 256;
        const int kc  = s >> 7;      // 0..3
        const int row = s & 127;     // dest row = src col
        const int sc  = blockIdx.y * 128 + row;
        const int sr  = blockIdx.x * 32 + kc * 8;
        bf16x8 hh, ll;
        #pragma unroll
        for (int j = 0; j < 8; ++j) {
            const float v = in[(size_t)(sr + j) * Ncols + sc];
            const bf16 b = (bf16)v;
            hh[j] = b; ll[j] = (bf16)(v - (float)b);
        }
        const int slot = row * 4 + ((kc + (row >> 1)) & 3);
        const size_t base = ((size_t)blockIdx.y * gridDim.x + blockIdx.x) * 4096
                          + slot * 8;
        *reinterpret_cast<bf16x8*>(h + base) = hh;
        *reinterpret_cast<bf16x8*>(l + base) = ll;
    }
}

// ------------------------------------------------------ gload_lds GEMM
// A,B hi/lo in tiled format. EPI==1: emit quantized V as tiled hi/lo pair.
// EPI==2: emit fp32 out + bias (row-major).
template<int EPI>
__global__ __launch_bounds__(256, 3)
void qlin_mfma3(const bf16* __restrict__ Ah_g, const bf16* __restrict__ Al_g,
                const bf16* __restrict__ Bh_g, const bf16* __restrict__ Bl_g,
                int M, int N, int K,
                float* __restrict__ Cf, bf16* __restrict__ Ch, bf16* __restrict__ Cl,
                const float* __restrict__ g_lx, const float* __restrict__ g_lw,
                const float* __restrict__ g_dx, const float* __restrict__ g_cb,
                const float* __restrict__ g_rcb, const float* __restrict__ g_bias)
{
    __shared__ __align__(16) bf16 sAh[4096], sAl[4096], sBh[4096], sBl[4096];
    __shared__ float s_cb[16], s_rcb[16], s_mid[15], s_rmid[15];

    const int tid = threadIdx.x;
    const int ln  = tid & 63;
    const int wid = tid >> 6;
    const int KT  = K >> 5;

    if (EPI == 1) {
        if (tid < 16) { s_cb[tid] = g_cb[tid]; s_rcb[tid] = g_rcb[tid]; }
        __syncthreads();
        if (tid < 15) {
            s_mid[tid]  = 0.5f * (s_cb[tid] + s_cb[tid + 1]);
            s_rmid[tid] = 0.5f * (s_rcb[tid] + s_rcb[tid + 1]);
        }
    }

    const size_t tileA0 = (size_t)blockIdx.y * KT;
    const size_t tileB0 = (size_t)blockIdx.x * KT;
    const int so = wid * 2048 + ln * 16;     // byte offset of this lane's slot

    auto STAGE = [&](int kt) {
        const size_t tA = (tileA0 + kt) * 8192;
        const size_t tB = (tileB0 + kt) * 8192;
        gload16((const char*)Ah_g + tA + so,        (char*)sAh + so);
        gload16((const char*)Ah_g + tA + so + 1024, (char*)sAh + so + 1024);
        gload16((const char*)Al_g + tA + so,        (char*)sAl + so);
        gload16((const char*)Al_g + tA + so + 1024, (char*)sAl + so + 1024);
        gload16((const char*)Bh_g + tB + so,        (char*)sBh + so);
        gload16((const char*)Bh_g + tB + so + 1024, (char*)sBh + so + 1024);
        gload16((const char*)Bl_g + tB + so,        (char*)sBl + so);
        gload16((const char*)Bl_g + tB + so + 1024, (char*)sBl + so + 1024);
    };

    const int wm = (wid >> 1) * 64;
    const int wn = (wid & 1) * 64;
    const int fr = ln & 15;
    const int q  = ln >> 4;

    f32x4 acc[4][4] = {};

    STAGE(0);
    __syncthreads();                          // drains vmcnt -> tile 0 ready

    for (int kt = 0; kt < KT; ++kt) {
        // read all fragments of tile kt (aligned b128, swizzled chunk)
        bf16x8 fAh[4], fAl[4], fBh[4], fBl[4];
        #pragma unroll
        for (int mi = 0; mi < 4; ++mi) {
            const int row = wm + mi * 16 + fr;
            const int off = row * 64 + (((q + (row >> 1)) & 3) << 4);
            fAh[mi] = *reinterpret_cast<const bf16x8*>((const char*)sAh + off);
            fAl[mi] = *reinterpret_cast<const bf16x8*>((const char*)sAl + off);
        }
        #pragma unroll
        for (int nj = 0; nj < 4; ++nj) {
            const int row = wn + nj * 16 + fr;
            const int off = row * 64 + (((q + (row >> 1)) & 3) << 4);
            fBh[nj] = *reinterpret_cast<const bf16x8*>((const char*)sBh + off);
            fBl[nj] = *reinterpret_cast<const bf16x8*>((const char*)sBl + off);
        }
        __syncthreads();                      // all reads done; LDS free
        if (kt + 1 < KT) STAGE(kt + 1);       // async loads fly under MFMA
        #pragma unroll
        for (int nj = 0; nj < 4; ++nj)
            #pragma unroll
            for (int mi = 0; mi < 4; ++mi) {
                acc[mi][nj] = __builtin_amdgcn_mfma_f32_16x16x32_bf16(
                    fAh[mi], fBh[nj], acc[mi][nj], 0, 0, 0);
                acc[mi][nj] = __builtin_amdgcn_mfma_f32_16x16x32_bf16(
                    fAh[mi], fBl[nj], acc[mi][nj], 0, 0, 0);
                acc[mi][nj] = __builtin_amdgcn_mfma_f32_16x16x32_bf16(
                    fAl[mi], fBh[nj], acc[mi][nj], 0, 0, 0);
            }
        __syncthreads();                      // drains vmcnt -> tile kt+1 ready
    }

    const int rloc = wm + q * 4;              // row-in-block base
    if (EPI == 1) {
        float mid[15], rmid[15];
        #pragma unroll
        for (int k = 0; k < 15; ++k) { mid[k] = s_mid[k]; rmid[k] = s_rmid[k]; }
        const int NT = N >> 5;
        #pragma unroll
        for (int nj = 0; nj < 4; ++nj) {
            const int c = blockIdx.x * BN + wn + nj * 16 + fr;
            const float lx = g_lx[c], lw = g_lw[c], dx = g_dx[c];
            const float slx = (fabsf(lx) < EPS_Q) ? EPS_Q : lx;
            const float sdx = (fabsf(dx) < EPS_Q) ? EPS_Q : dx;
            const float ilx = 1.0f / slx, isdx = 1.0f / sdx;
            const float c1 = lx * lw, c2 = dx * lw;
            const int tk = c >> 5, kc = (c >> 3) & 3, j = c & 7;
            #pragma unroll
            for (int mi = 0; mi < 4; ++mi)
                #pragma unroll
                for (int r = 0; r < 4; ++r) {
                    const float p = acc[mi][nj][r];
                    const float z = p * ilx;
                    int i1 = 0;
                    #pragma unroll
                    for (int k = 0; k < 15; ++k) i1 += (mid[k] < z) ? 1 : 0;
                    const float zq = s_cb[i1];
                    const float zr = (p - zq * lx) * isdx;
                    int i2 = 0;
                    #pragma unroll
                    for (int k = 0; k < 15; ++k) i2 += (rmid[k] < zr) ? 1 : 0;
                    const float qr = s_rcb[i2];
                    const float v  = zq * c1 + qr * c2;
                    const bf16  vh = (bf16)v;
                    const int rowInTile = rloc + mi * 16 + r;
                    const int slot = rowInTile * 4 + ((kc + (rowInTile >> 1)) & 3);
                    const size_t o = ((size_t)blockIdx.y * NT + tk) * 4096
                                   + slot * 8 + j;
                    Ch[o] = vh;
                    Cl[o] = (bf16)(v - (float)vh);
                }
        }
    } else {
        const int rbase = blockIdx.y * BM + rloc;
        #pragma unroll
        for (int nj = 0; nj < 4; ++nj) {
            const int c = blockIdx.x * BN + wn + nj * 16 + fr;
            const float bv = g_bias[c];
            #pragma unroll
            for (int mi = 0; mi < 4; ++mi)
                #pragma unroll
                for (int r = 0; r < 4; ++r)
                    Cf[(size_t)(rbase + mi * 16 + r) * N + c] = acc[mi][nj][r] + bv;
        }
    }
}

// --------------------------------------------- fallback (R7, validated path)
constexpr int FLDK = BK + 8;

__device__ __forceinline__ bf16x8 ld8(const bf16* p) {
    const bf16x4 a = *reinterpret_cast<const bf16x4*>(p);
    const bf16x4 b = *reinterpret_cast<const bf16x4*>(p + 4);
    return __builtin_shufflevector(a, b, 0, 1, 2, 3, 4, 5, 6, 7);
}

template<int EPI>
__global__ __launch_bounds__(256, 2)
void qlin_mfma(const float* __restrict__ A, const float* __restrict__ B,
               float* __restrict__ C, int M, int N, int K,
               const float* __restrict__ g_lx, const float* __restrict__ g_lw,
               const float* __restrict__ g_dx, const float* __restrict__ g_cb,
               const float* __restrict__ g_rcb, const float* __restrict__ g_bias)
{
    __shared__ bf16 Ah[BM][FLDK], Al[BM][FLDK], Bh[BN][FLDK], Bl[BN][FLDK];
    __shared__ float s_cb[16], s_rcb[16], s_mid[15], s_rmid[15];

    const int tid = threadIdx.x;
    const int bm  = blockIdx.y * BM;
    const int bn  = blockIdx.x * BN;

    if (EPI == 1) {
        if (tid < 16) { s_cb[tid] = g_cb[tid]; s_rcb[tid] = g_rcb[tid]; }
        __syncthreads();
        if (tid < 15) {
            s_mid[tid]  = 0.5f * (s_cb[tid] + s_cb[tid + 1]);
            s_rmid[tid] = 0.5f * (s_rcb[tid] + s_rcb[tid + 1]);
        }
    }

    const int am  = tid >> 1;
    const int ak0 = (tid & 1) * 16;
    const int bk  = (tid >> 4) * 2;
    const int bn0 = (tid & 15) * 8;
    const float* Abase = A + (size_t)(bm + am) * K + ak0;

    f32x4 rA[4], rB[4];
    auto LOADREGS = [&](int kt) {
        const float* ap = Abase + (size_t)kt * BK;
        #pragma unroll
        for (int q = 0; q < 4; ++q)
            rA[q] = *reinterpret_cast<const f32x4*>(ap + q * 4);
        #pragma unroll
        for (int q = 0; q < 4; ++q)
            rB[q] = *reinterpret_cast<const f32x4*>(
                B + (size_t)(kt * BK + bk + (q >> 1)) * N + bn + bn0 + (q & 1) * 4);
    };
    auto WRITELDS = [&]() {
        #pragma unroll
        for (int q = 0; q < 4; ++q) {
            bf16x4 h, l;
            #pragma unroll
            for (int e = 0; e < 4; ++e) {
                const float x = rA[q][e];
                const bf16  hh = (bf16)x;
                h[e] = hh;
                l[e] = (bf16)(x - (float)hh);
            }
            *reinterpret_cast<bf16x4*>(&Ah[am][ak0 + q * 4]) = h;
            *reinterpret_cast<bf16x4*>(&Al[am][ak0 + q * 4]) = l;
        }
        const int js = tid & 7;
        #pragma unroll
        for (int jj = 0; jj < 8; ++jj) {
            const int j = (jj + js) & 7;
            const float x0 = rB[(j >> 2)][j & 3];
            const float x1 = rB[2 + (j >> 2)][j & 3];
            const bf16 h0 = (bf16)x0, h1 = (bf16)x1;
            const bf16 l0 = (bf16)(x0 - (float)h0), l1 = (bf16)(x1 - (float)h1);
            bf16x2 ph = {h0, h1}, pl = {l0, l1};
            *reinterpret_cast<bf16x2*>(&Bh[bn0 + j][bk]) = ph;
            *reinterpret_cast<bf16x2*>(&Bl[bn0 + j][bk]) = pl;
        }
    };

    const int ln  = tid & 63;
    const int wid = tid >> 6;
    const int wm  = (wid >> 1) * 64;
    const int wn  = (wid & 1) * 64;
    const int fr  = ln & 15;
    const int k8  = (ln >> 4) * 8;

    f32x4 acc[4][4] = {};
    const int NK = K / BK;
    LOADREGS(0);
    for (int kt = 0; kt < NK; ++kt) {
        __syncthreads();
        WRITELDS();
        __syncthreads();
        if (kt + 1 < NK) LOADREGS(kt + 1);

        bf16x8 fAh[4], fAl[4];
        #pragma unroll
        for (int mi = 0; mi < 4; ++mi) {
            fAh[mi] = ld8(&Ah[wm + mi * 16 + fr][k8]);
            fAl[mi] = ld8(&Al[wm + mi * 16 + fr][k8]);
        }
        #pragma unroll
        for (int nj = 0; nj < 4; ++nj) {
            const bf16x8 fBh = ld8(&Bh[wn + nj * 16 + fr][k8]);
            const bf16x8 fBl = ld8(&Bl[wn + nj * 16 + fr][k8]);
            #pragma unroll
            for (int mi = 0; mi < 4; ++mi) {
                acc[mi][nj] = __builtin_amdgcn_mfma_f32_16x16x32_bf16(
                    fAh[mi], fBh, acc[mi][nj], 0, 0, 0);
                acc[mi][nj] = __builtin_amdgcn_mfma_f32_16x16x32_bf16(
                    fAh[mi], fBl, acc[mi][nj], 0, 0, 0);
                acc[mi][nj] = __builtin_amdgcn_mfma_f32_16x16x32_bf16(
                    fAl[mi], fBh, acc[mi][nj], 0, 0, 0);
            }
        }
    }

    const int rbase = bm + wm + (ln >> 4) * 4;
    if (EPI == 1) {
        float mid[15], rmid[15];
        #pragma unroll
        for (int k = 0; k < 15; ++k) { mid[k] = s_mid[k]; rmid[k] = s_rmid[k]; }
        #pragma unroll
        for (int nj = 0; nj < 4; ++nj) {
            const int c = bn + wn + nj * 16 + fr;
            const float lx = g_lx[c], lw = g_lw[c], dx = g_dx[c];
            const float slx = (fabsf(lx) < EPS_Q) ? EPS_Q : lx;
            const float sdx = (fabsf(dx) < EPS_Q) ? EPS_Q : dx;
            const float ilx = 1.0f / slx, isdx = 1.0f / sdx;
            const float c1 = lx * lw, c2 = dx * lw;
            #pragma unroll
            for (int mi = 0; mi < 4; ++mi)
                #pragma unroll
                for (int r = 0; r < 4; ++r) {
                    const float p = acc[mi][nj][r];
                    const float z = p * ilx;
                    int i1 = 0;
                    #pragma unroll
                    for (int k = 0; k < 15; ++k) i1 += (mid[k] < z) ? 1 : 0;
                    const float zq = s_cb[i1];
                    const float zr = (p - zq * lx) * isdx;
                    int i2 = 0;
                    #pragma unroll
                    for (int k = 0; k < 15; ++k) i2 += (rmid[k] < zr) ? 1 : 0;
                    const float qr = s_rcb[i2];
                    C[(size_t)(rbase + mi * 16 + r) * N + c] = zq * c1 + qr * c2;
                }
        }
    } else {
        #pragma unroll
        for (int nj = 0; nj < 4; ++nj) {
            const int c = bn + wn + nj * 16 + fr;
            const float bv = g_bias[c];
            #pragma unroll
            for (int mi = 0; mi < 4; ++mi)
                #pragma unroll
                for (int r = 0; r < 4; ++r)
                    C[(size_t)(rbase + mi * 16 + r) * N + c] = acc[mi][nj][r] + bv;
        }
    }
}

// ------------------------------------------------------------------- launch
extern "C" void kernel_launch(void* const* d_in, const int* in_sizes, int n_in,
                              void* d_out, int out_size, void* d_ws, size_t ws_size,
                              hipStream_t stream)
{
    const float* X    = (const float*)d_in[0];
    const float* U    = (const float*)d_in[1];
    const float* lx   = (const float*)d_in[2];
    const float* lw   = (const float*)d_in[3];
    const float* Zw   = (const float*)d_in[4];
    const float* cb   = (const float*)d_in[5];
    const float* dx   = (const float*)d_in[6];
    const float* rcb  = (const float*)d_in[7];
    const float* bias = (const float*)d_in[8];
    float* out = (float*)d_out;

    const int R    = in_sizes[2];
    const int DIN  = in_sizes[1] / R;
    const int M    = in_sizes[0] / DIN;
    const int DOUT = in_sizes[8];

    const size_t szX = (size_t)M * DIN * sizeof(bf16);
    const size_t szU = (size_t)DIN * R * sizeof(bf16);
    const size_t szZ = (size_t)R * DOUT * sizeof(bf16);
    const size_t szV = (size_t)M * R * sizeof(bf16);
    const size_t need = 2 * (szX + szU + szZ + szV);

    if (ws_size >= need) {
        char* w = (char*)d_ws;
        bf16* Xh = (bf16*)w;            w += szX;   // tiles [M/128][DIN/32]
        bf16* Xl = (bf16*)w;            w += szX;
        bf16* Uh = (bf16*)w;            w += szU;   // tiles [R/128][DIN/32]
        bf16* Ul = (bf16*)w;            w += szU;
        bf16* Zh = (bf16*)w;            w += szZ;   // tiles [DOUT/128][R/32]
        bf16* Zl = (bf16*)w;            w += szZ;
        bf16* Vh = (bf16*)w;            w += szV;   // tiles [M/128][R/32]
        bf16* Vl = (bf16*)w;

        split_ew_tiled<<<dim3(DIN / 32, M / 128), dim3(256), 0, stream>>>(
            X, Xh, Xl, DIN);
        split_tr_tiled<<<dim3(DIN / 32, R / 128), dim3(256), 0, stream>>>(
            U, Uh, Ul, R);
        split_tr_tiled<<<dim3(R / 32, DOUT / 128), dim3(256), 0, stream>>>(
            Zw, Zh, Zl, DOUT);

        qlin_mfma3<1><<<dim3(R / BN, M / BM), dim3(256), 0, stream>>>(
            Xh, Xl, Uh, Ul, M, R, DIN, nullptr, Vh, Vl,
            lx, lw, dx, cb, rcb, nullptr);
        qlin_mfma3<2><<<dim3(DOUT / BN, M / BM), dim3(256), 0, stream>>>(
            Vh, Vl, Zh, Zl, M, DOUT, R, out, nullptr, nullptr,
            nullptr, nullptr, nullptr, nullptr, nullptr, bias);
    } else {
        float* V = (float*)d_ws;
        qlin_mfma<1><<<dim3(R / BN, M / BM), dim3(256), 0, stream>>>(
            X, U, V, M, R, DIN, lx, lw, dx, cb, rcb, nullptr);
        qlin_mfma<2><<<dim3(DOUT / BN, M / BM), dim3(256), 0, stream>>>(
            V, Zw, out, M, DOUT, R, nullptr, nullptr, nullptr, nullptr, nullptr, bias);
    }
}

// Round 11
// 402.960 us; speedup vs baseline: 1.0329x; 1.0329x over previous
//
#include <hip/hip_runtime.h>
#include <math.h>

// R10 measured: (256,3) NEUTRAL, Occ stuck 23% -> HW reg quantum 64 rounds
// 140 live regs (76 arch + 64 acc AGPR) to 192 -> 2 waves/SIMD, can't rise.
// R11: 512-thread / 8-wave blocks, wave-tile 32x64 -> per-thread acc 32 regs,
// live ~100 -> fits the 128-reg bucket; __launch_bounds__(512,4) forces it.
// 16 waves/CU (2 blocks). Same tile format + MFMA pass order -> bit-identical
// (absmax must stay 0.0390625).

typedef __bf16 bf16;
typedef bf16 bf16x2 __attribute__((ext_vector_type(2)));
typedef bf16 bf16x4 __attribute__((ext_vector_type(4)));
typedef bf16 bf16x8 __attribute__((ext_vector_type(8)));
typedef float f32x4 __attribute__((ext_vector_type(4)));

#define EPS_Q 1e-8f

constexpr int BM = 128, BN = 128, BK = 32;

__device__ __forceinline__ void gload16(const void* g, void* l) {
    __builtin_amdgcn_global_load_lds(
        (const __attribute__((address_space(1))) unsigned int*)g,
        (__attribute__((address_space(3))) unsigned int*)l, 16, 0, 0);
}

// ---------------------------------------------------------------- prep
// X [MT*128][KT*32] f32 -> tiled hi/lo. grid (KT, MT)
__global__ __launch_bounds__(256)
void split_ew_tiled(const float* __restrict__ in, bf16* __restrict__ h,
                    bf16* __restrict__ l, int K)
{
    const int t = threadIdx.x;
    #pragma unroll
    for (int i = 0; i < 2; ++i) {
        const int s   = t + i * 256;
        const int row = s >> 2;
        const int kc  = s & 3;
        const float* src = in + (size_t)(blockIdx.y * 128 + row) * K
                              + blockIdx.x * 32 + kc * 8;
        const f32x4 v0 = *reinterpret_cast<const f32x4*>(src);
        const f32x4 v1 = *reinterpret_cast<const f32x4*>(src + 4);
        bf16x8 hh, ll;
        #pragma unroll
        for (int e = 0; e < 4; ++e) {
            const bf16 b0 = (bf16)v0[e];
            hh[e] = b0; ll[e] = (bf16)(v0[e] - (float)b0);
            const bf16 b1 = (bf16)v1[e];
            hh[e + 4] = b1; ll[e + 4] = (bf16)(v1[e] - (float)b1);
        }
        const int slot = row * 4 + ((kc + (row >> 1)) & 3);
        const size_t base = ((size_t)blockIdx.y * gridDim.x + blockIdx.x) * 4096
                          + slot * 8;
        *reinterpret_cast<bf16x8*>(h + base) = hh;
        *reinterpret_cast<bf16x8*>(l + base) = ll;
    }
}

// src [K][Ncols] f32 -> tiled hi/lo over [Ncols][K] (transpose). grid (KT, NT)
__global__ __launch_bounds__(256)
void split_tr_tiled(const float* __restrict__ in, bf16* __restrict__ h,
                    bf16* __restrict__ l, int Ncols)
{
    const int t = threadIdx.x;
    #pragma unroll
    for (int i = 0; i < 2; ++i) {
        const int s   = t + i * 256;
        const int kc  = s >> 7;      // 0..3
        const int row = s & 127;     // dest row = src col
        const int sc  = blockIdx.y * 128 + row;
        const int sr  = blockIdx.x * 32 + kc * 8;
        bf16x8 hh, ll;
        #pragma unroll
        for (int j = 0; j < 8; ++j) {
            const float v = in[(size_t)(sr + j) * Ncols + sc];
            const bf16 b = (bf16)v;
            hh[j] = b; ll[j] = (bf16)(v - (float)b);
        }
        const int slot = row * 4 + ((kc + (row >> 1)) & 3);
        const size_t base = ((size_t)blockIdx.y * gridDim.x + blockIdx.x) * 4096
                          + slot * 8;
        *reinterpret_cast<bf16x8*>(h + base) = hh;
        *reinterpret_cast<bf16x8*>(l + base) = ll;
    }
}

// ------------------------------------------------------ gload_lds GEMM
// 512 threads, 8 waves (4 row x 2 col), wave-tile 32x64.
// A,B hi/lo in tiled format. EPI==1: emit quantized V as tiled hi/lo pair.
// EPI==2: emit fp32 out + bias (row-major).
template<int EPI>
__global__ __launch_bounds__(512, 4)
void qlin_mfma4(const bf16* __restrict__ Ah_g, const bf16* __restrict__ Al_g,
                const bf16* __restrict__ Bh_g, const bf16* __restrict__ Bl_g,
                int M, int N, int K,
                float* __restrict__ Cf, bf16* __restrict__ Ch, bf16* __restrict__ Cl,
                const float* __restrict__ g_lx, const float* __restrict__ g_lw,
                const float* __restrict__ g_dx, const float* __restrict__ g_cb,
                const float* __restrict__ g_rcb, const float* __restrict__ g_bias)
{
    __shared__ __align__(16) bf16 sAh[4096], sAl[4096], sBh[4096], sBl[4096];
    __shared__ float s_cb[16], s_rcb[16], s_mid[15], s_rmid[15];

    const int tid = threadIdx.x;
    const int ln  = tid & 63;
    const int wid = tid >> 6;          // 0..7
    const int KT  = K >> 5;

    if (EPI == 1) {
        if (tid < 16) { s_cb[tid] = g_cb[tid]; s_rcb[tid] = g_rcb[tid]; }
        __syncthreads();
        if (tid < 15) {
            s_mid[tid]  = 0.5f * (s_cb[tid] + s_cb[tid + 1]);
            s_rmid[tid] = 0.5f * (s_rcb[tid] + s_rcb[tid + 1]);
        }
    }

    const size_t tileA0 = (size_t)blockIdx.y * KT;
    const size_t tileB0 = (size_t)blockIdx.x * KT;
    const int so = tid << 4;           // one 16B chunk per array per thread

    auto STAGE = [&](int kt) {
        const size_t tA = (tileA0 + kt) * 8192;
        const size_t tB = (tileB0 + kt) * 8192;
        gload16((const char*)Ah_g + tA + so, (char*)sAh + so);
        gload16((const char*)Al_g + tA + so, (char*)sAl + so);
        gload16((const char*)Bh_g + tB + so, (char*)sBh + so);
        gload16((const char*)Bl_g + tB + so, (char*)sBl + so);
    };

    const int wm = (wid >> 1) * 32;    // wave row base (0,32,64,96)
    const int wn = (wid & 1) * 64;     // wave col base (0,64)
    const int fr = ln & 15;
    const int q  = ln >> 4;

    f32x4 acc[2][4] = {};

    STAGE(0);
    __syncthreads();                   // drains vmcnt -> tile 0 ready

    for (int kt = 0; kt < KT; ++kt) {
        bf16x8 fAh[2], fAl[2];
        #pragma unroll
        for (int mi = 0; mi < 2; ++mi) {
            const int row = wm + mi * 16 + fr;
            const int off = row * 64 + (((q + (row >> 1)) & 3) << 4);
            fAh[mi] = *reinterpret_cast<const bf16x8*>((const char*)sAh + off);
            fAl[mi] = *reinterpret_cast<const bf16x8*>((const char*)sAl + off);
        }
        bf16x8 fBh[4], fBl[4];
        #pragma unroll
        for (int nj = 0; nj < 4; ++nj) {
            const int row = wn + nj * 16 + fr;
            const int off = row * 64 + (((q + (row >> 1)) & 3) << 4);
            fBh[nj] = *reinterpret_cast<const bf16x8*>((const char*)sBh + off);
            fBl[nj] = *reinterpret_cast<const bf16x8*>((const char*)sBl + off);
        }
        __syncthreads();               // all reads done; LDS free
        if (kt + 1 < KT) STAGE(kt + 1);   // async loads fly under MFMA
        #pragma unroll
        for (int nj = 0; nj < 4; ++nj)
            #pragma unroll
            for (int mi = 0; mi < 2; ++mi) {
                acc[mi][nj] = __builtin_amdgcn_mfma_f32_16x16x32_bf16(
                    fAh[mi], fBh[nj], acc[mi][nj], 0, 0, 0);
                acc[mi][nj] = __builtin_amdgcn_mfma_f32_16x16x32_bf16(
                    fAh[mi], fBl[nj], acc[mi][nj], 0, 0, 0);
                acc[mi][nj] = __builtin_amdgcn_mfma_f32_16x16x32_bf16(
                    fAl[mi], fBh[nj], acc[mi][nj], 0, 0, 0);
            }
        __syncthreads();               // drains vmcnt -> tile kt+1 ready
    }

    const int rloc = wm + q * 4;       // row-in-block base
    if (EPI == 1) {
        float mid[15], rmid[15];
        #pragma unroll
        for (int k = 0; k < 15; ++k) { mid[k] = s_mid[k]; rmid[k] = s_rmid[k]; }
        const int NT = N >> 5;
        #pragma unroll
        for (int nj = 0; nj < 4; ++nj) {
            const int c = blockIdx.x * BN + wn + nj * 16 + fr;
            const float lx = g_lx[c], lw = g_lw[c], dx = g_dx[c];
            const float slx = (fabsf(lx) < EPS_Q) ? EPS_Q : lx;
            const float sdx = (fabsf(dx) < EPS_Q) ? EPS_Q : dx;
            const float ilx = 1.0f / slx, isdx = 1.0f / sdx;
            const float c1 = lx * lw, c2 = dx * lw;
            const int tk = c >> 5, kc = (c >> 3) & 3, j = c & 7;
            #pragma unroll
            for (int mi = 0; mi < 2; ++mi)
                #pragma unroll
                for (int r = 0; r < 4; ++r) {
                    const float p = acc[mi][nj][r];
                    const float z = p * ilx;
                    int i1 = 0;
                    #pragma unroll
                    for (int k = 0; k < 15; ++k) i1 += (mid[k] < z) ? 1 : 0;
                    const float zq = s_cb[i1];
                    const float zr = (p - zq * lx) * isdx;
                    int i2 = 0;
                    #pragma unroll
                    for (int k = 0; k < 15; ++k) i2 += (rmid[k] < zr) ? 1 : 0;
                    const float qr = s_rcb[i2];
                    const float v  = zq * c1 + qr * c2;
                    const bf16  vh = (bf16)v;
                    const int rowInTile = rloc + mi * 16 + r;
                    const int slot = rowInTile * 4 + ((kc + (rowInTile >> 1)) & 3);
                    const size_t o = ((size_t)blockIdx.y * NT + tk) * 4096
                                   + slot * 8 + j;
                    Ch[o] = vh;
                    Cl[o] = (bf16)(v - (float)vh);
                }
        }
    } else {
        const int rbase = blockIdx.y * BM + rloc;
        #pragma unroll
        for (int nj = 0; nj < 4; ++nj) {
            const int c = blockIdx.x * BN + wn + nj * 16 + fr;
            const float bv = g_bias[c];
            #pragma unroll
            for (int mi = 0; mi < 2; ++mi)
                #pragma unroll
                for (int r = 0; r < 4; ++r)
                    Cf[(size_t)(rbase + mi * 16 + r) * N + c] = acc[mi][nj][r] + bv;
        }
    }
}

// --------------------------------------------- fallback (R7, validated path)
constexpr int FLDK = BK + 8;

__device__ __forceinline__ bf16x8 ld8(const bf16* p) {
    const bf16x4 a = *reinterpret_cast<const bf16x4*>(p);
    const bf16x4 b = *reinterpret_cast<const bf16x4*>(p + 4);
    return __builtin_shufflevector(a, b, 0, 1, 2, 3, 4, 5, 6, 7);
}

template<int EPI>
__global__ __launch_bounds__(256, 2)
void qlin_mfma(const float* __restrict__ A, const float* __restrict__ B,
               float* __restrict__ C, int M, int N, int K,
               const float* __restrict__ g_lx, const float* __restrict__ g_lw,
               const float* __restrict__ g_dx, const float* __restrict__ g_cb,
               const float* __restrict__ g_rcb, const float* __restrict__ g_bias)
{
    __shared__ bf16 Ah[BM][FLDK], Al[BM][FLDK], Bh[BN][FLDK], Bl[BN][FLDK];
    __shared__ float s_cb[16], s_rcb[16], s_mid[15], s_rmid[15];

    const int tid = threadIdx.x;
    const int bm  = blockIdx.y * BM;
    const int bn  = blockIdx.x * BN;

    if (EPI == 1) {
        if (tid < 16) { s_cb[tid] = g_cb[tid]; s_rcb[tid] = g_rcb[tid]; }
        __syncthreads();
        if (tid < 15) {
            s_mid[tid]  = 0.5f * (s_cb[tid] + s_cb[tid + 1]);
            s_rmid[tid] = 0.5f * (s_rcb[tid] + s_rcb[tid + 1]);
        }
    }

    const int am  = tid >> 1;
    const int ak0 = (tid & 1) * 16;
    const int bk  = (tid >> 4) * 2;
    const int bn0 = (tid & 15) * 8;
    const float* Abase = A + (size_t)(bm + am) * K + ak0;

    f32x4 rA[4], rB[4];
    auto LOADREGS = [&](int kt) {
        const float* ap = Abase + (size_t)kt * BK;
        #pragma unroll
        for (int q = 0; q < 4; ++q)
            rA[q] = *reinterpret_cast<const f32x4*>(ap + q * 4);
        #pragma unroll
        for (int q = 0; q < 4; ++q)
            rB[q] = *reinterpret_cast<const f32x4*>(
                B + (size_t)(kt * BK + bk + (q >> 1)) * N + bn + bn0 + (q & 1) * 4);
    };
    auto WRITELDS = [&]() {
        #pragma unroll
        for (int q = 0; q < 4; ++q) {
            bf16x4 h, l;
            #pragma unroll
            for (int e = 0; e < 4; ++e) {
                const float x = rA[q][e];
                const bf16  hh = (bf16)x;
                h[e] = hh;
                l[e] = (bf16)(x - (float)hh);
            }
            *reinterpret_cast<bf16x4*>(&Ah[am][ak0 + q * 4]) = h;
            *reinterpret_cast<bf16x4*>(&Al[am][ak0 + q * 4]) = l;
        }
        const int js = tid & 7;
        #pragma unroll
        for (int jj = 0; jj < 8; ++jj) {
            const int j = (jj + js) & 7;
            const float x0 = rB[(j >> 2)][j & 3];
            const float x1 = rB[2 + (j >> 2)][j & 3];
            const bf16 h0 = (bf16)x0, h1 = (bf16)x1;
            const bf16 l0 = (bf16)(x0 - (float)h0), l1 = (bf16)(x1 - (float)h1);
            bf16x2 ph = {h0, h1}, pl = {l0, l1};
            *reinterpret_cast<bf16x2*>(&Bh[bn0 + j][bk]) = ph;
            *reinterpret_cast<bf16x2*>(&Bl[bn0 + j][bk]) = pl;
        }
    };

    const int ln  = tid & 63;
    const int wid = tid >> 6;
    const int wm  = (wid >> 1) * 64;
    const int wn  = (wid & 1) * 64;
    const int fr  = ln & 15;
    const int k8  = (ln >> 4) * 8;

    f32x4 acc[4][4] = {};
    const int NK = K / BK;
    LOADREGS(0);
    for (int kt = 0; kt < NK; ++kt) {
        __syncthreads();
        WRITELDS();
        __syncthreads();
        if (kt + 1 < NK) LOADREGS(kt + 1);

        bf16x8 fAh[4], fAl[4];
        #pragma unroll
        for (int mi = 0; mi < 4; ++mi) {
            fAh[mi] = ld8(&Ah[wm + mi * 16 + fr][k8]);
            fAl[mi] = ld8(&Al[wm + mi * 16 + fr][k8]);
        }
        #pragma unroll
        for (int nj = 0; nj < 4; ++nj) {
            const bf16x8 fBh = ld8(&Bh[wn + nj * 16 + fr][k8]);
            const bf16x8 fBl = ld8(&Bl[wn + nj * 16 + fr][k8]);
            #pragma unroll
            for (int mi = 0; mi < 4; ++mi) {
                acc[mi][nj] = __builtin_amdgcn_mfma_f32_16x16x32_bf16(
                    fAh[mi], fBh, acc[mi][nj], 0, 0, 0);
                acc[mi][nj] = __builtin_amdgcn_mfma_f32_16x16x32_bf16(
                    fAh[mi], fBl, acc[mi][nj], 0, 0, 0);
                acc[mi][nj] = __builtin_amdgcn_mfma_f32_16x16x32_bf16(
                    fAl[mi], fBh, acc[mi][nj], 0, 0, 0);
            }
        }
    }

    const int rbase = bm + wm + (ln >> 4) * 4;
    if (EPI == 1) {
        float mid[15], rmid[15];
        #pragma unroll
        for (int k = 0; k < 15; ++k) { mid[k] = s_mid[k]; rmid[k] = s_rmid[k]; }
        #pragma unroll
        for (int nj = 0; nj < 4; ++nj) {
            const int c = bn + wn + nj * 16 + fr;
            const float lx = g_lx[c], lw = g_lw[c], dx = g_dx[c];
            const float slx = (fabsf(lx) < EPS_Q) ? EPS_Q : lx;
            const float sdx = (fabsf(dx) < EPS_Q) ? EPS_Q : dx;
            const float ilx = 1.0f / slx, isdx = 1.0f / sdx;
            const float c1 = lx * lw, c2 = dx * lw;
            #pragma unroll
            for (int mi = 0; mi < 4; ++mi)
                #pragma unroll
                for (int r = 0; r < 4; ++r) {
                    const float p = acc[mi][nj][r];
                    const float z = p * ilx;
                    int i1 = 0;
                    #pragma unroll
                    for (int k = 0; k < 15; ++k) i1 += (mid[k] < z) ? 1 : 0;
                    const float zq = s_cb[i1];
                    const float zr = (p - zq * lx) * isdx;
                    int i2 = 0;
                    #pragma unroll
                    for (int k = 0; k < 15; ++k) i2 += (rmid[k] < zr) ? 1 : 0;
                    const float qr = s_rcb[i2];
                    C[(size_t)(rbase + mi * 16 + r) * N + c] = zq * c1 + qr * c2;
                }
        }
    } else {
        #pragma unroll
        for (int nj = 0; nj < 4; ++nj) {
            const int c = bn + wn + nj * 16 + fr;
            const float bv = g_bias[c];
            #pragma unroll
            for (int mi = 0; mi < 4; ++mi)
                #pragma unroll
                for (int r = 0; r < 4; ++r)
                    C[(size_t)(rbase + mi * 16 + r) * N + c] = acc[mi][nj][r] + bv;
        }
    }
}

// ------------------------------------------------------------------- launch
extern "C" void kernel_launch(void* const* d_in, const int* in_sizes, int n_in,
                              void* d_out, int out_size, void* d_ws, size_t ws_size,
                              hipStream_t stream)
{
    const float* X    = (const float*)d_in[0];
    const float* U    = (const float*)d_in[1];
    const float* lx   = (const float*)d_in[2];
    const float* lw   = (const float*)d_in[3];
    const float* Zw   = (const float*)d_in[4];
    const float* cb   = (const float*)d_in[5];
    const float* dx   = (const float*)d_in[6];
    const float* rcb  = (const float*)d_in[7];
    const float* bias = (const float*)d_in[8];
    float* out = (float*)d_out;

    const int R    = in_sizes[2];
    const int DIN  = in_sizes[1] / R;
    const int M    = in_sizes[0] / DIN;
    const int DOUT = in_sizes[8];

    const size_t szX = (size_t)M * DIN * sizeof(bf16);
    const size_t szU = (size_t)DIN * R * sizeof(bf16);
    const size_t szZ = (size_t)R * DOUT * sizeof(bf16);
    const size_t szV = (size_t)M * R * sizeof(bf16);
    const size_t need = 2 * (szX + szU + szZ + szV);

    if (ws_size >= need) {
        char* w = (char*)d_ws;
        bf16* Xh = (bf16*)w;            w += szX;   // tiles [M/128][DIN/32]
        bf16* Xl = (bf16*)w;            w += szX;
        bf16* Uh = (bf16*)w;            w += szU;   // tiles [R/128][DIN/32]
        bf16* Ul = (bf16*)w;            w += szU;
        bf16* Zh = (bf16*)w;            w += szZ;   // tiles [DOUT/128][R/32]
        bf16* Zl = (bf16*)w;            w += szZ;
        bf16* Vh = (bf16*)w;            w += szV;   // tiles [M/128][R/32]
        bf16* Vl = (bf16*)w;

        split_ew_tiled<<<dim3(DIN / 32, M / 128), dim3(256), 0, stream>>>(
            X, Xh, Xl, DIN);
        split_tr_tiled<<<dim3(DIN / 32, R / 128), dim3(256), 0, stream>>>(
            U, Uh, Ul, R);
        split_tr_tiled<<<dim3(R / 32, DOUT / 128), dim3(256), 0, stream>>>(
            Zw, Zh, Zl, DOUT);

        qlin_mfma4<1><<<dim3(R / BN, M / BM), dim3(512), 0, stream>>>(
            Xh, Xl, Uh, Ul, M, R, DIN, nullptr, Vh, Vl,
            lx, lw, dx, cb, rcb, nullptr);
        qlin_mfma4<2><<<dim3(DOUT / BN, M / BM), dim3(512), 0, stream>>>(
            Vh, Vl, Zh, Zl, M, DOUT, R, out, nullptr, nullptr,
            nullptr, nullptr, nullptr, nullptr, nullptr, bias);
    } else {
        float* V = (float*)d_ws;
        qlin_mfma<1><<<dim3(R / BN, M / BM), dim3(256), 0, stream>>>(
            X, U, V, M, R, DIN, lx, lw, dx, cb, rcb, nullptr);
        qlin_mfma<2><<<dim3(DOUT / BN, M / BM), dim3(256), 0, stream>>>(
            V, Zw, out, M, DOUT, R, nullptr, nullptr, nullptr, nullptr, nullptr, bias);
    }
}